// Round 3
// baseline (388.147 us; speedup 1.0000x reference)
//
#include <hip/hip_runtime.h>
#include <stdint.h>

#define N_ANCHORS   200000
#define NUM_CLASSES 91
#define PRED_STRIDE 95      // 4 loc + 91 classes
#define MAX_DET     100
#define CAP         4096    // candidate capacity (sorted in LDS), power of 2
#define M_TARGET    3600    // desired top-M before NMS (<= CAP)
#define NBUCKETS    65536   // histogram over top 16 bits of score float
#define N_TILES     3125    // 200000 / 64 exactly

// ---------------------------------------------------------------- zero scratch
__global__ __launch_bounds__(256) void zero_kernel(unsigned int* __restrict__ hist,
                                                   int* __restrict__ ctr) {
  int i = blockIdx.x * 256 + threadIdx.x;
  if (i < NBUCKETS) hist[i] = 0u;
  if (i == 0) ctr[0] = 0;
}

// ---------------------------------------------------------------- decode + score
// One wave per 64-anchor tile. Tile's 6080 dwords are contiguous in `pred`:
// stage lane-coalesced into LDS rows padded to 97 (97%32==1 -> processing reads
// at lane*97+c hit bank (lane+c)%32: 2-way aliasing only, which is free).
__global__ __launch_bounds__(128) void decode_kernel(
    const float* __restrict__ pred, const float* __restrict__ dbx,
    float4* __restrict__ boxes, unsigned long long* __restrict__ keys,
    unsigned int* __restrict__ hist)
{
  __shared__ float tile[2][64 * 97];            // 49,664 B; one half per wave
  const int wv   = threadIdx.x >> 6;
  const int lane = threadIdx.x & 63;
  const int w    = blockIdx.x * 2 + wv;         // tile index == global wave id
  if (w >= N_TILES) return;                     // no barriers below: safe exit
  float* T = tile[wv];
  const float* src = pred + (size_t)w * (64 * PRED_STRIDE);

  // coalesced stage: dword k = j*64+lane -> row k/95, col k%95
  for (int j = 0; j < PRED_STRIDE; ++j) {
    int k = j * 64 + lane;
    float v = src[k];
    int row = k / PRED_STRIDE;
    int col = k - row * PRED_STRIDE;
    T[row * 97 + col] = v;
  }
  // all 64 lanes' ds_writes complete before any lane's ds_read (same wave,
  // no cross-wave sharing). Consumers are ds_reads, which "memory" orders.
  asm volatile("s_waitcnt lgkmcnt(0)" ::: "memory");

  const float* R = T + lane * 97;               // this lane's anchor row

  // softmax-max over 91 logits; score = 1/sum(exp(l - max))
  float lg[NUM_CLASSES];
#pragma unroll
  for (int j = 0; j < NUM_CLASSES; ++j) lg[j] = R[4 + j];
  float m = lg[0]; int am = 0;
#pragma unroll
  for (int j = 1; j < NUM_CLASSES; ++j) { if (lg[j] > m) { m = lg[j]; am = j; } }
  float s = 0.f;
#pragma unroll
  for (int j = 0; j < NUM_CLASSES; ++j) s += expf(lg[j] - m);
  float score = 1.0f / s;

  // box decode: loc*var, cxcywh -> corners, clip to [0,512]
  const int gi = w * 64 + lane;
  float4 d = ((const float4*)dbx)[gi];          // (cx, cy, w, h), coalesced
  float lx = R[0] * 0.1f, ly = R[1] * 0.1f, lw = R[2] * 0.2f, lh = R[3] * 0.2f;
  float cx = lx * d.z + d.x;
  float cy = ly * d.w + d.y;
  float bw = expf(lw) * d.z;
  float bh = expf(lh) * d.w;
  float x1 = fminf(fmaxf(cx - 0.5f * bw, 0.f), 512.f);
  float y1 = fminf(fmaxf(cy - 0.5f * bh, 0.f), 512.f);
  float x2 = fminf(fmaxf(cx + 0.5f * bw, 0.f), 512.f);
  float y2 = fminf(fmaxf(cy + 0.5f * bh, 0.f), 512.f);
  boxes[gi] = make_float4(x1, y1, x2, y2);

  // sort key: score bits high (positive float -> monotone uint),
  // ~(idx<<7|cls) low => ties resolve to LOWEST index (matches jnp.argmax).
  bool valid = (am != 0) && (score >= 0.02f);
  unsigned int sb = __float_as_uint(score);
  unsigned int payload = ~(((unsigned int)gi << 7) | (unsigned int)am);
  unsigned long long key = valid ? (((unsigned long long)sb << 32) | payload) : 0ull;
  keys[gi] = key;
  if (valid) atomicAdd(&hist[sb >> 16], 1u);
}

// ---------------------------------------------------------------- find threshold
// Largest bucket T with suffix(T) >= M_TARGET; if suffix(T) > CAP use T+1
// (then suffix(T+1) < M_TARGET <= CAP). Selected set is a strict score-prefix.
// Floor: selected >= CAP - maxbucket (~1000 of 198k) >> worst-case NMS
// consumption (~161 at the geometric bound p<=3%).
__global__ __launch_bounds__(1024) void thresh_kernel(const unsigned int* __restrict__ hist,
                                                      unsigned int* __restrict__ thr)
{
  __shared__ unsigned int csum[1024];
  int t = threadIdx.x;
  int base = t * 64;
  unsigned int s = 0;
  for (int j = 0; j < 64; ++j) s += hist[base + j];
  csum[t] = s;
  __syncthreads();
  for (int off = 1; off < 1024; off <<= 1) {     // reversed Hillis-Steele suffix
    unsigned int v = (t + off < 1024) ? csum[t + off] : 0u;
    __syncthreads();
    csum[t] += v;
    __syncthreads();
  }
  unsigned int mine  = csum[t];
  unsigned int after = (t == 1023) ? 0u : csum[t + 1];
  if (mine >= M_TARGET && (t == 1023 || after < M_TARGET)) {
    unsigned int running = after;
    unsigned int thrv = 0u;
    for (int b = base + 63; b >= base; --b) {
      running += hist[b];
      if (running >= M_TARGET) {                 // largest b with suffix(b)>=M
        if (running > CAP) thrv = ((unsigned int)(b + 1)) << 16;
        else               thrv = ((unsigned int)b) << 16;
        break;
      }
    }
    thr[0] = thrv;
  }
  if (t == 0 && csum[0] < M_TARGET) thr[0] = 0u; // fewer than M valid: take all
}

// ---------------------------------------------------------------- compact candidates
__global__ __launch_bounds__(256) void compact_kernel(
    const unsigned long long* __restrict__ keys, const unsigned int* __restrict__ thr,
    unsigned long long* __restrict__ cand, int* __restrict__ ctr)
{
  int i = blockIdx.x * 256 + threadIdx.x;
  if (i >= N_ANCHORS) return;
  unsigned long long k = keys[i];
  if (k != 0ull) {
    unsigned int sb = (unsigned int)(k >> 32);
    if (sb >= thr[0]) {
      int pos = atomicAdd(ctr, 1);
      if (pos < CAP) cand[pos] = k;              // threshold guarantees <= CAP
    }
  }
}

// ---------------------------------------------------------------- sort + NMS + output
__global__ __launch_bounds__(1024) void nms_kernel(
    const unsigned long long* __restrict__ cand, const int* __restrict__ ctr,
    const float4* __restrict__ boxes, float* __restrict__ out)
{
  __shared__ unsigned long long sk[CAP];         // 32 KiB
  __shared__ float4 abox[MAX_DET];
  __shared__ float aarea[MAX_DET];
  __shared__ unsigned long long akey[MAX_DET];
  __shared__ int acount;

  int K = ctr[0]; if (K > CAP) K = CAP;
  for (int t = threadIdx.x; t < CAP; t += 1024)
    sk[t] = (t < K) ? cand[t] : 0ull;            // 0-pad sinks to tail
  __syncthreads();

  // bitonic sort, descending; 12 stages, 78 passes
  for (int k = 2; k <= CAP; k <<= 1) {
    for (int j = k >> 1; j > 0; j >>= 1) {
      for (int t = threadIdx.x; t < CAP; t += 1024) {
        int l = t ^ j;
        if (l > t) {
          unsigned long long a = sk[t], b = sk[l];
          bool up = ((t & k) == 0);
          bool sw = up ? (a < b) : (a > b);
          if (sw) { sk[t] = b; sk[l] = a; }
        }
      }
      __syncthreads();
    }
  }
  __syncthreads();

  // wave-0 sequential accept over sorted prefix, 64 candidates per group.
  // Equivalence to reference greedy NMS: suppressed boxes never suppress
  // others and IoU is symmetric, so scanning by descending score with
  // accept-iff-no-accepted-overlap reproduces the argmax loop exactly.
  if (threadIdx.x < 64) {
    int lane = threadIdx.x;
    int ac = 0;
    for (int gbase = 0; gbase < CAP && ac < MAX_DET; gbase += 64) {
      if (gbase >= K) break;
      __asm__ __volatile__("" ::: "memory");
      unsigned long long key = sk[gbase + lane];
      bool alive = (key != 0ull);
      float4 b = make_float4(0.f, 0.f, 0.f, 0.f);
      float area = 0.f;
      if (alive) {
        unsigned int pay = ~(unsigned int)key;   // (idx<<7)|cls
        int idx = (int)(pay >> 7);
        b = boxes[idx];
        area = (b.z - b.x) * (b.w - b.y);
      }
      for (int a2 = 0; a2 < ac; ++a2) {          // prefilter vs accepted
        if (alive) {
          float4 ab = abox[a2];
          float lx = fmaxf(ab.x, b.x), ly = fmaxf(ab.y, b.y);
          float rx = fminf(ab.z, b.z), ry = fminf(ab.w, b.w);
          float iw = fmaxf(rx - lx, 0.f), ih = fmaxf(ry - ly, 0.f);
          float inter = iw * ih;
          float iou = inter / (aarea[a2] + area - inter + 1e-9f);
          if (iou > 0.5f) alive = false;
        }
      }
      while (ac < MAX_DET) {                     // in-group ordered resolution
        unsigned long long mv = __ballot(alive);
        if (mv == 0ull) break;
        int first = __ffsll(mv) - 1;
        float wx1 = __shfl(b.x, first), wy1 = __shfl(b.y, first);
        float wx2 = __shfl(b.z, first), wy2 = __shfl(b.w, first);
        float wa  = __shfl(area, first);
        if (lane == first) {
          abox[ac] = b; aarea[ac] = area; akey[ac] = key;
          alive = false;
        }
        __asm__ __volatile__("" ::: "memory");
        if (alive) {
          float lx = fmaxf(wx1, b.x), ly = fmaxf(wy1, b.y);
          float rx = fminf(wx2, b.z), ry = fminf(wy2, b.w);
          float iw = fmaxf(rx - lx, 0.f), ih = fmaxf(ry - ly, 0.f);
          float inter = iw * ih;
          float iou = inter / (wa + area - inter + 1e-9f);
          if (iou > 0.5f) alive = false;
        }
        ++ac;
      }
    }
    if (lane == 0) acount = ac;
  }
  __syncthreads();

  // outputs: boxes[100*4] | ids[100] | scores[100] (ids as float, -1 invalid)
  int t = threadIdx.x;
  if (t < MAX_DET) {
    float bx1 = 0.f, by1 = 0.f, bx2 = 0.f, by2 = 0.f, idf = -1.f, sc = 0.f;
    if (t < acount) {
      unsigned long long key = akey[t];
      float4 b = abox[t];
      bx1 = b.x; by1 = b.y; bx2 = b.z; by2 = b.w;
      unsigned int pay = ~(unsigned int)key;
      int clsid = (int)(pay & 0x7Fu);
      idf = (float)(clsid - 1);
      sc = __uint_as_float((unsigned int)(key >> 32));
    }
    out[t * 4 + 0] = bx1; out[t * 4 + 1] = by1;
    out[t * 4 + 2] = bx2; out[t * 4 + 3] = by2;
    out[400 + t] = idf;
    out[500 + t] = sc;
  }
}

// ---------------------------------------------------------------- launch
extern "C" void kernel_launch(void* const* d_in, const int* in_sizes, int n_in,
                              void* d_out, int out_size, void* d_ws, size_t ws_size,
                              hipStream_t stream) {
  (void)in_sizes; (void)n_in; (void)out_size; (void)ws_size;
  const float* pred = (const float*)d_in[0];
  const float* dbx  = (const float*)d_in[1];
  float* out = (float*)d_out;

  char* ws = (char*)d_ws;
  float4*             boxes = (float4*)(ws);                        // 3,200,000 B
  unsigned long long* keys  = (unsigned long long*)(ws + 3200000);  // 1,600,000 B
  unsigned int*       hist  = (unsigned int*)(ws + 4800000);        //   262,144 B
  int*                ctr   = (int*)(ws + 5062144);                 //        16 B
  unsigned int*       thr   = (unsigned int*)(ws + 5062160);        //        16 B
  unsigned long long* cand  = (unsigned long long*)(ws + 5062176);  //    32,768 B

  hipLaunchKernelGGL(zero_kernel, dim3((NBUCKETS + 255) / 256), dim3(256), 0, stream,
                     hist, ctr);
  hipLaunchKernelGGL(decode_kernel, dim3((N_TILES + 1) / 2), dim3(128), 0, stream,
                     pred, dbx, boxes, keys, hist);
  hipLaunchKernelGGL(thresh_kernel, dim3(1), dim3(1024), 0, stream, hist, thr);
  hipLaunchKernelGGL(compact_kernel, dim3((N_ANCHORS + 255) / 256), dim3(256), 0, stream,
                     keys, thr, cand, ctr);
  hipLaunchKernelGGL(nms_kernel, dim3(1), dim3(1024), 0, stream,
                     cand, ctr, boxes, out);
}

// Round 5
// 252.949 us; speedup vs baseline: 1.5345x; 1.5345x over previous
//
#include <hip/hip_runtime.h>
#include <stdint.h>

#define N_ANCHORS   200000
#define NUM_CLASSES 91
#define PRED_STRIDE 95      // 4 loc + 91 classes
#define TILE_BYTES  24320   // 64 * 95 * 4
#define MAX_DET     100
#define CAP         4096    // candidate capacity (sorted in LDS), power of 2
#define M_TARGET    3600    // desired top-M before NMS (<= CAP)
#define NBUCKETS    65536   // histogram over top 16 bits of score float
#define NREP        8       // histogram replicas (atomic contention /8)
#define N_TILES     3125    // 200000 / 64 exactly

// async global->LDS, width 16 ONLY (the HW-measured lane-stride case:
// wave-uniform LDS base + lane*16; global source per-lane).
__device__ __forceinline__ void gload_lds16(const void* g, void* l) {
  __builtin_amdgcn_global_load_lds(
      (const __attribute__((address_space(1))) uint32_t*)g,
      (__attribute__((address_space(3))) uint32_t*)l, 16, 0, 0);
}

// ---------------------------------------------------------------- zero scratch
__global__ __launch_bounds__(256) void zero_kernel(unsigned int* __restrict__ hist,
                                                   int* __restrict__ ctr) {
  int i = blockIdx.x * 256 + threadIdx.x;
  if (i < NREP * NBUCKETS) hist[i] = 0u;
  if (i == 0) ctr[0] = 0;
}

// ---------------------------------------------------------------- decode + score
// One wave per 64-anchor tile; tile is 24,320 contiguous bytes of `pred`.
// Stage via width-16 global_load_lds into LINEAR [64][95] floats: row stride
// 95 % 32 == 31 -> per-lane row reads are 2-way bank-aliased only (free).
// 23 strips cover [0, 23552); an OVERLAPPED strip covers [23296, 24320)
// (overlap bytes identical, order-independent) -> no width-12, no overread.
__global__ __launch_bounds__(128) void decode_kernel(
    const float* __restrict__ pred, const float* __restrict__ dbx,
    float4* __restrict__ boxes, unsigned long long* __restrict__ keys,
    unsigned int* __restrict__ hist)
{
  __shared__ float tile[2][64 * PRED_STRIDE];   // 48,640 B -> 3 blocks/CU
  const int wv   = threadIdx.x >> 6;
  const int lane = threadIdx.x & 63;
  const int w    = blockIdx.x * 2 + wv;         // tile index == global wave id
  if (w >= N_TILES) return;                     // no barriers below: safe exit
  float* T = tile[wv];
  const char* src = (const char*)pred + (size_t)w * TILE_BYTES;  // 16B-aligned

#pragma unroll
  for (int q = 0; q < 23; ++q)
    gload_lds16(src + q * 1024 + lane * 16, &T[q * 256]);
  gload_lds16(src + 23296 + lane * 16, &T[5824]);   // 23296 = 1456*16 = 24320-1024
  asm volatile("s_waitcnt vmcnt(0)" ::: "memory");  // drain DMA (per-wave)
  __builtin_amdgcn_sched_barrier(0);                // rule #18 insurance

  const float* R = T + lane * PRED_STRIDE;      // this lane's anchor row

  // softmax-max over 91 logits; score = 1/sum(exp(l - max))
  float m = R[4]; int am = 0;
#pragma unroll
  for (int j = 1; j < NUM_CLASSES; ++j) {
    float v = R[4 + j];
    if (v > m) { m = v; am = j; }
  }
  float s = 0.f;
#pragma unroll
  for (int j = 0; j < NUM_CLASSES; ++j) s += expf(R[4 + j] - m);
  float score = 1.0f / s;

  // box decode: loc*var, cxcywh -> corners, clip to [0,512]
  const int gi = w * 64 + lane;
  float4 d = ((const float4*)dbx)[gi];          // (cx, cy, w, h), coalesced
  float lx = R[0] * 0.1f, ly = R[1] * 0.1f, lw = R[2] * 0.2f, lh = R[3] * 0.2f;
  float cx = lx * d.z + d.x;
  float cy = ly * d.w + d.y;
  float bw = expf(lw) * d.z;
  float bh = expf(lh) * d.w;
  float x1 = fminf(fmaxf(cx - 0.5f * bw, 0.f), 512.f);
  float y1 = fminf(fmaxf(cy - 0.5f * bh, 0.f), 512.f);
  float x2 = fminf(fmaxf(cx + 0.5f * bw, 0.f), 512.f);
  float y2 = fminf(fmaxf(cy + 0.5f * bh, 0.f), 512.f);
  boxes[gi] = make_float4(x1, y1, x2, y2);

  // sort key: score bits high (positive float -> monotone uint),
  // ~(idx<<7|cls) low => ties resolve to LOWEST index (matches jnp.argmax).
  bool valid = (am != 0) && (score >= 0.02f);
  unsigned int sb = __float_as_uint(score);
  unsigned int payload = ~(((unsigned int)gi << 7) | (unsigned int)am);
  unsigned long long key = valid ? (((unsigned long long)sb << 32) | payload) : 0ull;
  keys[gi] = key;
  if (valid) atomicAdd(&hist[(w & (NREP - 1)) * NBUCKETS + (sb >> 16)], 1u);
}

// ---------------------------------------------------------------- chunk sums
// Wave W sums buckets [W*64, W*64+64) across all replicas, coalesced.
__global__ __launch_bounds__(256) void chunksum_kernel(
    const unsigned int* __restrict__ hist, unsigned int* __restrict__ chunksum)
{
  int tid = blockIdx.x * 256 + threadIdx.x;     // 65536 threads = 1024 waves
  int W = tid >> 6, lane = tid & 63;
  unsigned int s = 0;
#pragma unroll
  for (int r = 0; r < NREP; ++r) s += hist[r * NBUCKETS + W * 64 + lane];
  for (int off = 32; off; off >>= 1) s += __shfl_down(s, off);
  if (lane == 0) chunksum[W] = s;
}

// ---------------------------------------------------------------- find threshold
// Largest bucket b* with suffix(b*) >= M_TARGET; if suffix(b*) > CAP use b*+1
// (then suffix(b*+1) < M_TARGET <= CAP). Selected set is a strict score-prefix.
// In-chunk refinement: parallel bucket totals -> LDS, then SERIAL walk by
// thread 0 (byte-identical logic to the round-3 version that passed).
__global__ __launch_bounds__(1024) void thresh_kernel(
    const unsigned int* __restrict__ hist, const unsigned int* __restrict__ chunksum,
    unsigned int* __restrict__ thr)
{
  __shared__ unsigned int csum[1024];
  __shared__ unsigned int cbuf[64];
  __shared__ int cstar;
  __shared__ unsigned int cafter;
  int t = threadIdx.x;
  csum[t] = chunksum[t];                        // coalesced 4KB
  if (t == 0) cstar = -1;
  __syncthreads();
  for (int off = 1; off < 1024; off <<= 1) {    // reversed Hillis-Steele suffix
    unsigned int v = (t + off < 1024) ? csum[t + off] : 0u;
    __syncthreads();
    csum[t] += v;
    __syncthreads();
  }
  unsigned int mine  = csum[t];
  unsigned int after = (t == 1023) ? 0u : csum[t + 1];
  if (mine >= M_TARGET && (t == 1023 || after < M_TARGET)) {
    cstar = t; cafter = after;                  // unique crossing chunk
  }
  if (t == 0 && csum[0] < M_TARGET) thr[0] = 0u; // fewer than M valid: take all
  __syncthreads();
  if (t < 64 && cstar >= 0) {
    int b = cstar * 64 + t;
    unsigned int cnt = 0;
#pragma unroll
    for (int r = 0; r < NREP; ++r) cnt += hist[r * NBUCKETS + b];
    cbuf[t] = cnt;
  }
  __syncthreads();
  if (t == 0 && cstar >= 0) {
    unsigned int running = cafter;              // < M_TARGET by construction
    unsigned int thrv = 0u;
    for (int i = 63; i >= 0; --i) {
      running += cbuf[i];
      if (running >= M_TARGET) {                // largest b with suffix(b)>=M
        unsigned int b = (unsigned int)(cstar * 64 + i);
        thrv = (running > CAP) ? ((b + 1) << 16) : (b << 16);
        break;
      }
    }
    thr[0] = thrv;
  }
}

// ---------------------------------------------------------------- compact candidates
__global__ __launch_bounds__(256) void compact_kernel(
    const unsigned long long* __restrict__ keys, const unsigned int* __restrict__ thr,
    unsigned long long* __restrict__ cand, int* __restrict__ ctr)
{
  int i = blockIdx.x * 256 + threadIdx.x;
  if (i >= N_ANCHORS) return;
  unsigned long long k = keys[i];
  if (k != 0ull) {
    unsigned int sb = (unsigned int)(k >> 32);
    if (sb >= thr[0]) {
      int pos = atomicAdd(ctr, 1);
      if (pos < CAP) cand[pos] = k;             // threshold guarantees <= CAP
    }
  }
}

// ---------------------------------------------------------------- sort + NMS + output
__global__ __launch_bounds__(1024) void nms_kernel(
    const unsigned long long* __restrict__ cand, const int* __restrict__ ctr,
    const float4* __restrict__ boxes, float* __restrict__ out)
{
  __shared__ unsigned long long sk[CAP];        // 32 KiB
  __shared__ float4 abox[MAX_DET];
  __shared__ float aarea[MAX_DET];
  __shared__ unsigned long long akey[MAX_DET];
  __shared__ int acount;

  int K = ctr[0]; if (K > CAP) K = CAP;
  for (int t = threadIdx.x; t < CAP; t += 1024)
    sk[t] = (t < K) ? cand[t] : 0ull;           // 0-pad sinks to tail
  __syncthreads();

  // bitonic sort, descending; 12 stages, 78 passes
  for (int k = 2; k <= CAP; k <<= 1) {
    for (int j = k >> 1; j > 0; j >>= 1) {
      for (int t = threadIdx.x; t < CAP; t += 1024) {
        int l = t ^ j;
        if (l > t) {
          unsigned long long a = sk[t], b = sk[l];
          bool up = ((t & k) == 0);
          bool sw = up ? (a < b) : (a > b);
          if (sw) { sk[t] = b; sk[l] = a; }
        }
      }
      __syncthreads();
    }
  }
  __syncthreads();

  // wave-0 sequential accept over sorted prefix, 64 candidates per group.
  // Equivalence to reference greedy NMS: suppressed boxes never suppress
  // others and IoU is symmetric, so scanning by descending score with
  // accept-iff-no-accepted-overlap reproduces the argmax loop exactly.
  if (threadIdx.x < 64) {
    int lane = threadIdx.x;
    int ac = 0;
    for (int gbase = 0; gbase < CAP && ac < MAX_DET; gbase += 64) {
      if (gbase >= K) break;
      __asm__ __volatile__("" ::: "memory");
      unsigned long long key = sk[gbase + lane];
      bool alive = (key != 0ull);
      float4 b = make_float4(0.f, 0.f, 0.f, 0.f);
      float area = 0.f;
      if (alive) {
        unsigned int pay = ~(unsigned int)key;  // (idx<<7)|cls
        int idx = (int)(pay >> 7);
        b = boxes[idx];
        area = (b.z - b.x) * (b.w - b.y);
      }
      for (int a2 = 0; a2 < ac; ++a2) {         // prefilter vs accepted
        if (alive) {
          float4 ab = abox[a2];
          float lx = fmaxf(ab.x, b.x), ly = fmaxf(ab.y, b.y);
          float rx = fminf(ab.z, b.z), ry = fminf(ab.w, b.w);
          float iw = fmaxf(rx - lx, 0.f), ih = fmaxf(ry - ly, 0.f);
          float inter = iw * ih;
          float iou = inter / (aarea[a2] + area - inter + 1e-9f);
          if (iou > 0.5f) alive = false;
        }
      }
      while (ac < MAX_DET) {                    // in-group ordered resolution
        unsigned long long mv = __ballot(alive);
        if (mv == 0ull) break;
        int first = __ffsll(mv) - 1;
        float wx1 = __shfl(b.x, first), wy1 = __shfl(b.y, first);
        float wx2 = __shfl(b.z, first), wy2 = __shfl(b.w, first);
        float wa  = __shfl(area, first);
        if (lane == first) {
          abox[ac] = b; aarea[ac] = area; akey[ac] = key;
          alive = false;
        }
        __asm__ __volatile__("" ::: "memory");
        if (alive) {
          float lx = fmaxf(wx1, b.x), ly = fmaxf(wy1, b.y);
          float rx = fminf(wx2, b.z), ry = fminf(wy2, b.w);
          float iw = fmaxf(rx - lx, 0.f), ih = fmaxf(ry - ly, 0.f);
          float inter = iw * ih;
          float iou = inter / (wa + area - inter + 1e-9f);
          if (iou > 0.5f) alive = false;
        }
        ++ac;
      }
    }
    if (lane == 0) acount = ac;
  }
  __syncthreads();

  // outputs: boxes[100*4] | ids[100] | scores[100] (ids as float, -1 invalid)
  int t = threadIdx.x;
  if (t < MAX_DET) {
    float bx1 = 0.f, by1 = 0.f, bx2 = 0.f, by2 = 0.f, idf = -1.f, sc = 0.f;
    if (t < acount) {
      unsigned long long key = akey[t];
      float4 b = abox[t];
      bx1 = b.x; by1 = b.y; bx2 = b.z; by2 = b.w;
      unsigned int pay = ~(unsigned int)key;
      int clsid = (int)(pay & 0x7Fu);
      idf = (float)(clsid - 1);
      sc = __uint_as_float((unsigned int)(key >> 32));
    }
    out[t * 4 + 0] = bx1; out[t * 4 + 1] = by1;
    out[t * 4 + 2] = bx2; out[t * 4 + 3] = by2;
    out[400 + t] = idf;
    out[500 + t] = sc;
  }
}

// ---------------------------------------------------------------- launch
extern "C" void kernel_launch(void* const* d_in, const int* in_sizes, int n_in,
                              void* d_out, int out_size, void* d_ws, size_t ws_size,
                              hipStream_t stream) {
  (void)in_sizes; (void)n_in; (void)out_size; (void)ws_size;
  const float* pred = (const float*)d_in[0];
  const float* dbx  = (const float*)d_in[1];
  float* out = (float*)d_out;

  char* ws = (char*)d_ws;
  float4*             boxes = (float4*)(ws);                        // 3,200,000 B
  unsigned long long* keys  = (unsigned long long*)(ws + 3200000);  // 1,600,000 B
  unsigned int*       hist  = (unsigned int*)(ws + 4800000);        // 2,097,152 B
  unsigned int*       csums = (unsigned int*)(ws + 6897152);        //     4,096 B
  int*                ctr   = (int*)(ws + 6901248);                 //        16 B
  unsigned int*       thr   = (unsigned int*)(ws + 6901264);        //        16 B
  unsigned long long* cand  = (unsigned long long*)(ws + 6901280);  //    32,768 B

  hipLaunchKernelGGL(zero_kernel, dim3((NREP * NBUCKETS) / 256), dim3(256), 0, stream,
                     hist, ctr);
  hipLaunchKernelGGL(decode_kernel, dim3((N_TILES + 1) / 2), dim3(128), 0, stream,
                     pred, dbx, boxes, keys, hist);
  hipLaunchKernelGGL(chunksum_kernel, dim3(NBUCKETS / 256), dim3(256), 0, stream,
                     hist, csums);
  hipLaunchKernelGGL(thresh_kernel, dim3(1), dim3(1024), 0, stream,
                     hist, csums, thr);
  hipLaunchKernelGGL(compact_kernel, dim3((N_ANCHORS + 255) / 256), dim3(256), 0, stream,
                     keys, thr, cand, ctr);
  hipLaunchKernelGGL(nms_kernel, dim3(1), dim3(1024), 0, stream,
                     cand, ctr, boxes, out);
}

// Round 9
// 220.343 us; speedup vs baseline: 1.7616x; 1.1480x over previous
//
#include <hip/hip_runtime.h>
#include <stdint.h>

#define N_ANCHORS   200000
#define NUM_CLASSES 91
#define PRED_STRIDE 95      // 4 loc + 91 classes
#define TILE_BYTES  24320   // 64 * 95 * 4
#define MAX_DET     100
#define CAP         4096    // candidate capacity (sorted), power of 2
#define M_TARGET    3600    // desired top-M before NMS (<= CAP)
#define NBUCKETS    65536   // histogram over top 16 bits of score float
#define NREP        8       // histogram replicas (atomic contention /8)
#define N_TILES     3125    // 200000 / 64 exactly

// async global->LDS, width 16 ONLY (the HW-measured lane-stride case:
// wave-uniform LDS base + lane*16; global source per-lane).
__device__ __forceinline__ void gload_lds16(const void* g, void* l) {
  __builtin_amdgcn_global_load_lds(
      (const __attribute__((address_space(1))) uint32_t*)g,
      (__attribute__((address_space(3))) uint32_t*)l, 16, 0, 0);
}

__device__ __forceinline__ unsigned long long umax64(unsigned long long a,
                                                     unsigned long long b) {
  return a > b ? a : b;
}
__device__ __forceinline__ unsigned long long umin64(unsigned long long a,
                                                     unsigned long long b) {
  return a < b ? a : b;
}
// compare-exchange: up=true -> a gets max (descending pair)
__device__ __forceinline__ void cex(unsigned long long& a, unsigned long long& b,
                                    bool up) {
  unsigned long long mx = a > b ? a : b;
  unsigned long long mn = a > b ? b : a;
  a = up ? mx : mn;
  b = up ? mn : mx;
}

// ---------------------------------------------------------------- zero scratch
__global__ __launch_bounds__(256) void zero_kernel(unsigned int* __restrict__ hist,
                                                   int* __restrict__ ctr) {
  int i = blockIdx.x * 256 + threadIdx.x;
  if (i < NREP * NBUCKETS) hist[i] = 0u;
  if (i == 0) ctr[0] = 0;
}

// ---------------------------------------------------------------- decode + score
// One wave per 64-anchor tile; tile is 24,320 contiguous bytes of `pred`.
// Stage via width-16 global_load_lds into LINEAR [64][95] floats: row stride
// 95 % 32 == 31 -> per-lane row reads are 2-way bank-aliased only (free).
// 23 strips cover [0, 23552); an OVERLAPPED strip covers [23296, 24320).
__global__ __launch_bounds__(128) void decode_kernel(
    const float* __restrict__ pred, const float* __restrict__ dbx,
    float4* __restrict__ boxes, unsigned long long* __restrict__ keys,
    unsigned int* __restrict__ hist)
{
  __shared__ float tile[2][64 * PRED_STRIDE];   // 48,640 B -> 3 blocks/CU
  const int wv   = threadIdx.x >> 6;
  const int lane = threadIdx.x & 63;
  const int w    = blockIdx.x * 2 + wv;         // tile index == global wave id
  if (w >= N_TILES) return;                     // no barriers below: safe exit
  float* T = tile[wv];
  const char* src = (const char*)pred + (size_t)w * TILE_BYTES;  // 16B-aligned

#pragma unroll
  for (int q = 0; q < 23; ++q)
    gload_lds16(src + q * 1024 + lane * 16, &T[q * 256]);
  gload_lds16(src + 23296 + lane * 16, &T[5824]);   // tail, overlapped strip
  asm volatile("s_waitcnt vmcnt(0)" ::: "memory");  // drain DMA (per-wave)
  __builtin_amdgcn_sched_barrier(0);                // rule #18 insurance

  const float* R = T + lane * PRED_STRIDE;      // this lane's anchor row

  // softmax-max over 91 logits; score = 1/sum(exp(l - max))
  float m = R[4]; int am = 0;
#pragma unroll
  for (int j = 1; j < NUM_CLASSES; ++j) {
    float v = R[4 + j];
    if (v > m) { m = v; am = j; }
  }
  float s = 0.f;
#pragma unroll
  for (int j = 0; j < NUM_CLASSES; ++j) s += expf(R[4 + j] - m);
  float score = 1.0f / s;

  // box decode: loc*var, cxcywh -> corners, clip to [0,512]
  const int gi = w * 64 + lane;
  float4 d = ((const float4*)dbx)[gi];          // (cx, cy, w, h), coalesced
  float lx = R[0] * 0.1f, ly = R[1] * 0.1f, lw = R[2] * 0.2f, lh = R[3] * 0.2f;
  float cx = lx * d.z + d.x;
  float cy = ly * d.w + d.y;
  float bw = expf(lw) * d.z;
  float bh = expf(lh) * d.w;
  float x1 = fminf(fmaxf(cx - 0.5f * bw, 0.f), 512.f);
  float y1 = fminf(fmaxf(cy - 0.5f * bh, 0.f), 512.f);
  float x2 = fminf(fmaxf(cx + 0.5f * bw, 0.f), 512.f);
  float y2 = fminf(fmaxf(cy + 0.5f * bh, 0.f), 512.f);
  boxes[gi] = make_float4(x1, y1, x2, y2);

  // sort key: score bits high (positive float -> monotone uint),
  // ~(idx<<7|cls) low => ties resolve to LOWEST index (matches jnp.argmax).
  bool valid = (am != 0) && (score >= 0.02f);
  unsigned int sb = __float_as_uint(score);
  unsigned int payload = ~(((unsigned int)gi << 7) | (unsigned int)am);
  unsigned long long key = valid ? (((unsigned long long)sb << 32) | payload) : 0ull;
  keys[gi] = key;
  if (valid) atomicAdd(&hist[(w & (NREP - 1)) * NBUCKETS + (sb >> 16)], 1u);
}

// ---------------------------------------------------------------- chunk sums
__global__ __launch_bounds__(256) void chunksum_kernel(
    const unsigned int* __restrict__ hist, unsigned int* __restrict__ chunksum)
{
  int tid = blockIdx.x * 256 + threadIdx.x;     // 65536 threads = 1024 waves
  int W = tid >> 6, lane = tid & 63;
  unsigned int s = 0;
#pragma unroll
  for (int r = 0; r < NREP; ++r) s += hist[r * NBUCKETS + W * 64 + lane];
  for (int off = 32; off; off >>= 1) s += __shfl_down(s, off);
  if (lane == 0) chunksum[W] = s;
}

// ---------------------------------------------------------------- find threshold
// Largest bucket b* with suffix(b*) >= M_TARGET; if suffix(b*) > CAP use b*+1
// (then suffix(b*+1) < M_TARGET <= CAP). Selected set is a strict score-prefix.
__global__ __launch_bounds__(1024) void thresh_kernel(
    const unsigned int* __restrict__ hist, const unsigned int* __restrict__ chunksum,
    unsigned int* __restrict__ thr)
{
  __shared__ unsigned int csum[1024];
  __shared__ unsigned int cbuf[64];
  __shared__ int cstar;
  __shared__ unsigned int cafter;
  int t = threadIdx.x;
  csum[t] = chunksum[t];                        // coalesced 4KB
  if (t == 0) cstar = -1;
  __syncthreads();
  for (int off = 1; off < 1024; off <<= 1) {    // reversed Hillis-Steele suffix
    unsigned int v = (t + off < 1024) ? csum[t + off] : 0u;
    __syncthreads();
    csum[t] += v;
    __syncthreads();
  }
  unsigned int mine  = csum[t];
  unsigned int after = (t == 1023) ? 0u : csum[t + 1];
  if (mine >= M_TARGET && (t == 1023 || after < M_TARGET)) {
    cstar = t; cafter = after;                  // unique crossing chunk
  }
  if (t == 0 && csum[0] < M_TARGET) thr[0] = 0u; // fewer than M valid: take all
  __syncthreads();
  if (t < 64 && cstar >= 0) {
    int b = cstar * 64 + t;
    unsigned int cnt = 0;
#pragma unroll
    for (int r = 0; r < NREP; ++r) cnt += hist[r * NBUCKETS + b];
    cbuf[t] = cnt;
  }
  __syncthreads();
  if (t == 0 && cstar >= 0) {
    unsigned int running = cafter;              // < M_TARGET by construction
    unsigned int thrv = 0u;
    for (int i = 63; i >= 0; --i) {
      running += cbuf[i];
      if (running >= M_TARGET) {                // largest b with suffix(b)>=M
        unsigned int b = (unsigned int)(cstar * 64 + i);
        thrv = (running > CAP) ? ((b + 1) << 16) : (b << 16);
        break;
      }
    }
    thr[0] = thrv;
  }
}

// ---------------------------------------------------------------- compact candidates
__global__ __launch_bounds__(256) void compact_kernel(
    const unsigned long long* __restrict__ keys, const unsigned int* __restrict__ thr,
    unsigned long long* __restrict__ cand, int* __restrict__ ctr)
{
  int i = blockIdx.x * 256 + threadIdx.x;
  if (i >= N_ANCHORS) return;
  unsigned long long k = keys[i];
  if (k != 0ull) {
    unsigned int sb = (unsigned int)(k >> 32);
    if (sb >= thr[0]) {
      int pos = atomicAdd(ctr, 1);
      if (pos < CAP) cand[pos] = k;             // threshold guarantees <= CAP
    }
  }
}

// ---------------------------------------------------------------- sort + NMS + output
// Register-resident bitonic sort: i = 4t+e, 4 keys/thread.
//   j==1,2      : in-register compare-exchange
//   j==4..128   : partner thread t^(j>>2) is in-wave -> __shfl_xor
//   j>=256      : cross-wave -> LDS exchange (only 10 of 78 passes)
// Comparator identical to the proven LDS sort: up=((i&k)==0) -> lower index
// keeps max (descending; 0-pads sink). up is e-independent for k>=4 since
// e occupies bits 0-1 and (4t+e)&k == (4t)&k; k==2/j==1 special-cased.
__global__ __launch_bounds__(1024) void nms_kernel(
    const unsigned long long* __restrict__ cand, const int* __restrict__ ctr,
    const float4* __restrict__ boxes, float* __restrict__ out)
{
  __shared__ unsigned long long sk[CAP];        // 32 KiB
  __shared__ float4 abox[MAX_DET];
  __shared__ float aarea[MAX_DET];
  __shared__ unsigned long long akey[MAX_DET];
  __shared__ int acount;

  const int t = threadIdx.x;
  int K = ctr[0]; if (K > CAP) K = CAP;

  unsigned long long r0, r1, r2, r3;
  {
    const int b = 4 * t;
    r0 = (b + 0 < K) ? cand[b + 0] : 0ull;
    r1 = (b + 1 < K) ? cand[b + 1] : 0ull;
    r2 = (b + 2 < K) ? cand[b + 2] : 0ull;
    r3 = (b + 3 < K) ? cand[b + 3] : 0ull;
  }

  for (int k = 2; k <= CAP; k <<= 1) {
    for (int j = k >> 1; j > 0; j >>= 1) {
      const bool up = (((4 * t) & k) == 0);     // valid for k>=4 (see note)
      if (j >= 256) {                           // cross-wave: LDS exchange
        sk[4 * t + 0] = r0; sk[4 * t + 1] = r1;
        sk[4 * t + 2] = r2; sk[4 * t + 3] = r3;
        __syncthreads();
        const int pt = 4 * (t ^ (j >> 2));
        unsigned long long p0 = sk[pt + 0], p1 = sk[pt + 1];
        unsigned long long p2 = sk[pt + 2], p3 = sk[pt + 3];
        const bool takemax = (up == ((t & (j >> 2)) == 0));
        r0 = takemax ? umax64(r0, p0) : umin64(r0, p0);
        r1 = takemax ? umax64(r1, p1) : umin64(r1, p1);
        r2 = takemax ? umax64(r2, p2) : umin64(r2, p2);
        r3 = takemax ? umax64(r3, p3) : umin64(r3, p3);
        __syncthreads();
      } else if (j >= 4) {                      // in-wave: shfl exchange
        const int lx = j >> 2;                  // 1..32 < 64
        const bool takemax = (up == ((t & lx) == 0));
        unsigned long long p;
        p = __shfl_xor(r0, lx); r0 = takemax ? umax64(r0, p) : umin64(r0, p);
        p = __shfl_xor(r1, lx); r1 = takemax ? umax64(r1, p) : umin64(r1, p);
        p = __shfl_xor(r2, lx); r2 = takemax ? umax64(r2, p) : umin64(r2, p);
        p = __shfl_xor(r3, lx); r3 = takemax ? umax64(r3, p) : umin64(r3, p);
      } else if (j == 2) {                      // in-thread, pairs (0,2),(1,3)
        cex(r0, r2, up); cex(r1, r3, up);
      } else {                                  // j == 1, pairs (0,1),(2,3)
        if (k == 2) { cex(r0, r1, true); cex(r2, r3, false); }  // e-dependent
        else        { cex(r0, r1, up);   cex(r2, r3, up);   }
      }
    }
  }
  sk[4 * t + 0] = r0; sk[4 * t + 1] = r1;
  sk[4 * t + 2] = r2; sk[4 * t + 3] = r3;
  __syncthreads();

  // wave-0 sequential accept over sorted prefix, 64 candidates per group.
  // Equivalence to reference greedy NMS: suppressed boxes never suppress
  // others and IoU is symmetric, so scanning by descending score with
  // accept-iff-no-accepted-overlap reproduces the argmax loop exactly.
  if (threadIdx.x < 64) {
    int lane = threadIdx.x;
    int ac = 0;
    for (int gbase = 0; gbase < CAP && ac < MAX_DET; gbase += 64) {
      if (gbase >= K) break;
      __asm__ __volatile__("" ::: "memory");
      unsigned long long key = sk[gbase + lane];
      bool alive = (key != 0ull);
      float4 b = make_float4(0.f, 0.f, 0.f, 0.f);
      float area = 0.f;
      if (alive) {
        unsigned int pay = ~(unsigned int)key;  // (idx<<7)|cls
        int idx = (int)(pay >> 7);
        b = boxes[idx];
        area = (b.z - b.x) * (b.w - b.y);
      }
      for (int a2 = 0; a2 < ac; ++a2) {         // prefilter vs accepted
        if (alive) {
          float4 ab = abox[a2];
          float lx = fmaxf(ab.x, b.x), ly = fmaxf(ab.y, b.y);
          float rx = fminf(ab.z, b.z), ry = fminf(ab.w, b.w);
          float iw = fmaxf(rx - lx, 0.f), ih = fmaxf(ry - ly, 0.f);
          float inter = iw * ih;
          float iou = inter / (aarea[a2] + area - inter + 1e-9f);
          if (iou > 0.5f) alive = false;
        }
      }
      while (ac < MAX_DET) {                    // in-group ordered resolution
        unsigned long long mv = __ballot(alive);
        if (mv == 0ull) break;
        int first = __ffsll(mv) - 1;
        float wx1 = __shfl(b.x, first), wy1 = __shfl(b.y, first);
        float wx2 = __shfl(b.z, first), wy2 = __shfl(b.w, first);
        float wa  = __shfl(area, first);
        if (lane == first) {
          abox[ac] = b; aarea[ac] = area; akey[ac] = key;
          alive = false;
        }
        __asm__ __volatile__("" ::: "memory");
        if (alive) {
          float lx = fmaxf(wx1, b.x), ly = fmaxf(wy1, b.y);
          float rx = fminf(wx2, b.z), ry = fminf(wy2, b.w);
          float iw = fmaxf(rx - lx, 0.f), ih = fmaxf(ry - ly, 0.f);
          float inter = iw * ih;
          float iou = inter / (wa + area - inter + 1e-9f);
          if (iou > 0.5f) alive = false;
        }
        ++ac;
      }
    }
    if (lane == 0) acount = ac;
  }
  __syncthreads();

  // outputs: boxes[100*4] | ids[100] | scores[100] (ids as float, -1 invalid)
  if (t < MAX_DET) {
    float bx1 = 0.f, by1 = 0.f, bx2 = 0.f, by2 = 0.f, idf = -1.f, sc = 0.f;
    if (t < acount) {
      unsigned long long key = akey[t];
      float4 b = abox[t];
      bx1 = b.x; by1 = b.y; bx2 = b.z; by2 = b.w;
      unsigned int pay = ~(unsigned int)key;
      int clsid = (int)(pay & 0x7Fu);
      idf = (float)(clsid - 1);
      sc = __uint_as_float((unsigned int)(key >> 32));
    }
    out[t * 4 + 0] = bx1; out[t * 4 + 1] = by1;
    out[t * 4 + 2] = bx2; out[t * 4 + 3] = by2;
    out[400 + t] = idf;
    out[500 + t] = sc;
  }
}

// ---------------------------------------------------------------- launch
extern "C" void kernel_launch(void* const* d_in, const int* in_sizes, int n_in,
                              void* d_out, int out_size, void* d_ws, size_t ws_size,
                              hipStream_t stream) {
  (void)in_sizes; (void)n_in; (void)out_size; (void)ws_size;
  const float* pred = (const float*)d_in[0];
  const float* dbx  = (const float*)d_in[1];
  float* out = (float*)d_out;

  char* ws = (char*)d_ws;
  float4*             boxes = (float4*)(ws);                        // 3,200,000 B
  unsigned long long* keys  = (unsigned long long*)(ws + 3200000);  // 1,600,000 B
  unsigned int*       hist  = (unsigned int*)(ws + 4800000);        // 2,097,152 B
  unsigned int*       csums = (unsigned int*)(ws + 6897152);        //     4,096 B
  int*                ctr   = (int*)(ws + 6901248);                 //        16 B
  unsigned int*       thr   = (unsigned int*)(ws + 6901264);        //        16 B
  unsigned long long* cand  = (unsigned long long*)(ws + 6901280);  //    32,768 B

  hipLaunchKernelGGL(zero_kernel, dim3((NREP * NBUCKETS) / 256), dim3(256), 0, stream,
                     hist, ctr);
  hipLaunchKernelGGL(decode_kernel, dim3((N_TILES + 1) / 2), dim3(128), 0, stream,
                     pred, dbx, boxes, keys, hist);
  hipLaunchKernelGGL(chunksum_kernel, dim3(NBUCKETS / 256), dim3(256), 0, stream,
                     hist, csums);
  hipLaunchKernelGGL(thresh_kernel, dim3(1), dim3(1024), 0, stream,
                     hist, csums, thr);
  hipLaunchKernelGGL(compact_kernel, dim3((N_ANCHORS + 255) / 256), dim3(256), 0, stream,
                     keys, thr, cand, ctr);
  hipLaunchKernelGGL(nms_kernel, dim3(1), dim3(1024), 0, stream,
                     cand, ctr, boxes, out);
}

// Round 10
// 211.449 us; speedup vs baseline: 1.8357x; 1.0421x over previous
//
#include <hip/hip_runtime.h>
#include <stdint.h>

#define N_ANCHORS   200000
#define NUM_CLASSES 91
#define PRED_STRIDE 95      // 4 loc + 91 classes
#define TILE_BYTES  24320   // 64 * 95 * 4
#define MAX_DET     100
#define CAP         4096    // candidate capacity, power of 2
#define CAPS        1024    // per-block sort slice (CAP/4)
#define M_TARGET    3600    // desired top-M before NMS (<= CAP)
#define NBUCKETS    65536   // histogram over top 16 bits of score float
#define NREP        8       // histogram replicas (atomic contention /8)
#define N_TILES     3125    // 200000 / 64 exactly

// async global->LDS, width 16 ONLY (the HW-measured lane-stride case:
// wave-uniform LDS base + lane*16; global source per-lane).
__device__ __forceinline__ void gload_lds16(const void* g, void* l) {
  __builtin_amdgcn_global_load_lds(
      (const __attribute__((address_space(1))) uint32_t*)g,
      (__attribute__((address_space(3))) uint32_t*)l, 16, 0, 0);
}

__device__ __forceinline__ unsigned long long umax64(unsigned long long a,
                                                     unsigned long long b) {
  return a > b ? a : b;
}
__device__ __forceinline__ unsigned long long umin64(unsigned long long a,
                                                     unsigned long long b) {
  return a < b ? a : b;
}
// compare-exchange: up=true -> a gets max (descending pair)
__device__ __forceinline__ void cex(unsigned long long& a, unsigned long long& b,
                                    bool up) {
  unsigned long long mx = a > b ? a : b;
  unsigned long long mn = a > b ? b : a;
  a = up ? mx : mn;
  b = up ? mn : mx;
}

// merge-path: emit 8 outputs of descending merge A(nA) ∪ B(nB) at offset d.
// A-priority on ties (ties occur only among 0-pads). Binary search finds
// i = #A-elements among top-d; probes stay in range by construction.
__device__ __forceinline__ void merge8(
    const unsigned long long* __restrict__ A, int nA,
    const unsigned long long* __restrict__ B, int nB,
    unsigned long long* __restrict__ C, int d)
{
  int lo = d - nB; if (lo < 0) lo = 0;
  int hi = d < nA ? d : nA;
  while (lo < hi) {
    int mid = (lo + hi) >> 1;
    if (A[mid] < B[d - 1 - mid]) hi = mid; else lo = mid + 1;
  }
  int i = lo, j = d - lo;
#pragma unroll
  for (int e = 0; e < 8; ++e) {
    bool takeA = (j >= nB) || (i < nA && A[i] >= B[j]);
    unsigned long long v = takeA ? A[i] : B[j];
    C[d + e] = v;
    if (takeA) ++i; else ++j;
  }
}

// ---------------------------------------------------------------- zero scratch
__global__ __launch_bounds__(256) void zero_kernel(unsigned int* __restrict__ hist,
                                                   int* __restrict__ ctr) {
  int i = blockIdx.x * 256 + threadIdx.x;
  if (i < NREP * NBUCKETS) hist[i] = 0u;
  if (i == 0) ctr[0] = 0;
}

// ---------------------------------------------------------------- decode + score
// One wave per 64-anchor tile; tile is 24,320 contiguous bytes of `pred`.
// Stage via width-16 global_load_lds into LINEAR [64][95] floats: row stride
// 95 % 32 == 31 -> per-lane row reads are 2-way bank-aliased only (free).
// 23 strips cover [0, 23552); an OVERLAPPED strip covers [23296, 24320).
__global__ __launch_bounds__(128) void decode_kernel(
    const float* __restrict__ pred, const float* __restrict__ dbx,
    float4* __restrict__ boxes, unsigned long long* __restrict__ keys,
    unsigned int* __restrict__ hist)
{
  __shared__ float tile[2][64 * PRED_STRIDE];   // 48,640 B -> 3 blocks/CU
  const int wv   = threadIdx.x >> 6;
  const int lane = threadIdx.x & 63;
  const int w    = blockIdx.x * 2 + wv;         // tile index == global wave id
  if (w >= N_TILES) return;                     // no barriers below: safe exit
  float* T = tile[wv];
  const char* src = (const char*)pred + (size_t)w * TILE_BYTES;  // 16B-aligned

#pragma unroll
  for (int q = 0; q < 23; ++q)
    gload_lds16(src + q * 1024 + lane * 16, &T[q * 256]);
  gload_lds16(src + 23296 + lane * 16, &T[5824]);   // tail, overlapped strip
  asm volatile("s_waitcnt vmcnt(0)" ::: "memory");  // drain DMA (per-wave)
  __builtin_amdgcn_sched_barrier(0);                // rule #18 insurance

  const float* R = T + lane * PRED_STRIDE;      // this lane's anchor row

  // softmax-max over 91 logits; score = 1/sum(exp(l - max))
  float m = R[4]; int am = 0;
#pragma unroll
  for (int j = 1; j < NUM_CLASSES; ++j) {
    float v = R[4 + j];
    if (v > m) { m = v; am = j; }
  }
  float s = 0.f;
#pragma unroll
  for (int j = 0; j < NUM_CLASSES; ++j) s += expf(R[4 + j] - m);
  float score = 1.0f / s;

  // box decode: loc*var, cxcywh -> corners, clip to [0,512]
  const int gi = w * 64 + lane;
  float4 d = ((const float4*)dbx)[gi];          // (cx, cy, w, h), coalesced
  float lx = R[0] * 0.1f, ly = R[1] * 0.1f, lw = R[2] * 0.2f, lh = R[3] * 0.2f;
  float cx = lx * d.z + d.x;
  float cy = ly * d.w + d.y;
  float bw = expf(lw) * d.z;
  float bh = expf(lh) * d.w;
  float x1 = fminf(fmaxf(cx - 0.5f * bw, 0.f), 512.f);
  float y1 = fminf(fmaxf(cy - 0.5f * bh, 0.f), 512.f);
  float x2 = fminf(fmaxf(cx + 0.5f * bw, 0.f), 512.f);
  float y2 = fminf(fmaxf(cy + 0.5f * bh, 0.f), 512.f);
  boxes[gi] = make_float4(x1, y1, x2, y2);

  // sort key: score bits high (positive float -> monotone uint),
  // ~(idx<<7|cls) low => ties resolve to LOWEST index (matches jnp.argmax).
  bool valid = (am != 0) && (score >= 0.02f);
  unsigned int sb = __float_as_uint(score);
  unsigned int payload = ~(((unsigned int)gi << 7) | (unsigned int)am);
  unsigned long long key = valid ? (((unsigned long long)sb << 32) | payload) : 0ull;
  keys[gi] = key;
  if (valid) atomicAdd(&hist[(w & (NREP - 1)) * NBUCKETS + (sb >> 16)], 1u);
}

// ---------------------------------------------------------------- chunk sums
__global__ __launch_bounds__(256) void chunksum_kernel(
    const unsigned int* __restrict__ hist, unsigned int* __restrict__ chunksum)
{
  int tid = blockIdx.x * 256 + threadIdx.x;     // 65536 threads = 1024 waves
  int W = tid >> 6, lane = tid & 63;
  unsigned int s = 0;
#pragma unroll
  for (int r = 0; r < NREP; ++r) s += hist[r * NBUCKETS + W * 64 + lane];
  for (int off = 32; off; off >>= 1) s += __shfl_down(s, off);
  if (lane == 0) chunksum[W] = s;
}

// ---------------------------------------------------------------- find threshold
// Largest bucket b* with suffix(b*) >= M_TARGET; if suffix(b*) > CAP use b*+1
// (then suffix(b*+1) < M_TARGET <= CAP). Selected set is a strict score-prefix.
__global__ __launch_bounds__(1024) void thresh_kernel(
    const unsigned int* __restrict__ hist, const unsigned int* __restrict__ chunksum,
    unsigned int* __restrict__ thr)
{
  __shared__ unsigned int csum[1024];
  __shared__ unsigned int cbuf[64];
  __shared__ int cstar;
  __shared__ unsigned int cafter;
  int t = threadIdx.x;
  csum[t] = chunksum[t];                        // coalesced 4KB
  if (t == 0) cstar = -1;
  __syncthreads();
  for (int off = 1; off < 1024; off <<= 1) {    // reversed Hillis-Steele suffix
    unsigned int v = (t + off < 1024) ? csum[t + off] : 0u;
    __syncthreads();
    csum[t] += v;
    __syncthreads();
  }
  unsigned int mine  = csum[t];
  unsigned int after = (t == 1023) ? 0u : csum[t + 1];
  if (mine >= M_TARGET && (t == 1023 || after < M_TARGET)) {
    cstar = t; cafter = after;                  // unique crossing chunk
  }
  if (t == 0 && csum[0] < M_TARGET) thr[0] = 0u; // fewer than M valid: take all
  __syncthreads();
  if (t < 64 && cstar >= 0) {
    int b = cstar * 64 + t;
    unsigned int cnt = 0;
#pragma unroll
    for (int r = 0; r < NREP; ++r) cnt += hist[r * NBUCKETS + b];
    cbuf[t] = cnt;
  }
  __syncthreads();
  if (t == 0 && cstar >= 0) {
    unsigned int running = cafter;              // < M_TARGET by construction
    unsigned int thrv = 0u;
    for (int i = 63; i >= 0; --i) {
      running += cbuf[i];
      if (running >= M_TARGET) {                // largest b with suffix(b)>=M
        unsigned int b = (unsigned int)(cstar * 64 + i);
        thrv = (running > CAP) ? ((b + 1) << 16) : (b << 16);
        break;
      }
    }
    thr[0] = thrv;
  }
}

// ---------------------------------------------------------------- compact candidates
__global__ __launch_bounds__(256) void compact_kernel(
    const unsigned long long* __restrict__ keys, const unsigned int* __restrict__ thr,
    unsigned long long* __restrict__ cand, int* __restrict__ ctr)
{
  int i = blockIdx.x * 256 + threadIdx.x;
  if (i >= N_ANCHORS) return;
  unsigned long long k = keys[i];
  if (k != 0ull) {
    unsigned int sb = (unsigned int)(k >> 32);
    if (sb >= thr[0]) {
      int pos = atomicAdd(ctr, 1);
      if (pos < CAP) cand[pos] = k;             // threshold guarantees <= CAP
    }
  }
}

// ---------------------------------------------------------------- 4-way slice sort
// grid=4, block=256: block b sorts cand[b*1024 : b*1024+1024] IN PLACE,
// descending, 0-padded past K. Same register-bitonic structure as proven:
// i_local = 4t+e; reg j<=2, shfl j=4..128 (lx=j>>2<=32, in-wave), LDS j>=256
// (lx in {64,128}, cross-wave). Only 3 LDS passes for 1024 keys.
__global__ __launch_bounds__(256) void sort4_kernel(
    unsigned long long* __restrict__ cand, const int* __restrict__ ctr)
{
  __shared__ unsigned long long sk[CAPS];       // 8 KiB
  const int t = threadIdx.x;                    // 0..255
  const int base = blockIdx.x * CAPS;
  int K = ctr[0]; if (K > CAP) K = CAP;

  unsigned long long r0, r1, r2, r3;
  {
    const int b = base + 4 * t;
    r0 = (b + 0 < K) ? cand[b + 0] : 0ull;
    r1 = (b + 1 < K) ? cand[b + 1] : 0ull;
    r2 = (b + 2 < K) ? cand[b + 2] : 0ull;
    r3 = (b + 3 < K) ? cand[b + 3] : 0ull;
  }

  for (int k = 2; k <= CAPS; k <<= 1) {
    for (int j = k >> 1; j > 0; j >>= 1) {
      const bool up = (((4 * t) & k) == 0);
      if (j >= 256) {                           // cross-wave: LDS exchange
        sk[4 * t + 0] = r0; sk[4 * t + 1] = r1;
        sk[4 * t + 2] = r2; sk[4 * t + 3] = r3;
        __syncthreads();
        const int pt = 4 * (t ^ (j >> 2));
        unsigned long long p0 = sk[pt + 0], p1 = sk[pt + 1];
        unsigned long long p2 = sk[pt + 2], p3 = sk[pt + 3];
        const bool takemax = (up == ((t & (j >> 2)) == 0));
        r0 = takemax ? umax64(r0, p0) : umin64(r0, p0);
        r1 = takemax ? umax64(r1, p1) : umin64(r1, p1);
        r2 = takemax ? umax64(r2, p2) : umin64(r2, p2);
        r3 = takemax ? umax64(r3, p3) : umin64(r3, p3);
        __syncthreads();
      } else if (j >= 4) {                      // in-wave: shfl exchange
        const int lx = j >> 2;                  // 1..32 < 64
        const bool takemax = (up == ((t & lx) == 0));
        unsigned long long p;
        p = __shfl_xor(r0, lx); r0 = takemax ? umax64(r0, p) : umin64(r0, p);
        p = __shfl_xor(r1, lx); r1 = takemax ? umax64(r1, p) : umin64(r1, p);
        p = __shfl_xor(r2, lx); r2 = takemax ? umax64(r2, p) : umin64(r2, p);
        p = __shfl_xor(r3, lx); r3 = takemax ? umax64(r3, p) : umin64(r3, p);
      } else if (j == 2) {                      // in-thread, pairs (0,2),(1,3)
        cex(r0, r2, up); cex(r1, r3, up);
      } else {                                  // j == 1, pairs (0,1),(2,3)
        if (k == 2) { cex(r0, r1, true); cex(r2, r3, false); }  // e-dependent
        else        { cex(r0, r1, up);   cex(r2, r3, up);   }
      }
    }
  }
  // write back full slice (pads included -> cand[0:4096] fully defined)
  {
    const int b = base + 4 * t;
    cand[b + 0] = r0; cand[b + 1] = r1;
    cand[b + 2] = r2; cand[b + 3] = r3;
  }
}

// ---------------------------------------------------------------- merge + NMS + output
__global__ __launch_bounds__(512) void nms_kernel(
    const unsigned long long* __restrict__ cand, const int* __restrict__ ctr,
    const float4* __restrict__ boxes, float* __restrict__ out)
{
  __shared__ unsigned long long ska[CAP];       // 32 KiB
  __shared__ unsigned long long skb[CAP];       // 32 KiB
  __shared__ float4 abox[MAX_DET];
  __shared__ float aarea[MAX_DET];
  __shared__ unsigned long long akey[MAX_DET];
  __shared__ int acount;

  const int t = threadIdx.x;
  int K = ctr[0]; if (K > CAP) K = CAP;

  for (int i = t; i < CAP; i += 512) ska[i] = cand[i];  // 4 sorted slices
  __syncthreads();

  // Round 1: (ska[0:1024] ∪ ska[1024:2048]) -> skb[0:2048]  (threads 0-255)
  //          (ska[2048:3072] ∪ ska[3072:4096]) -> skb[2048:4096] (256-511)
  {
    const int half = t >> 8;                    // 0 or 1
    const int tt = t & 255;                     // 0..255 -> 8 outputs each
    merge8(&ska[half * 2048], CAPS, &ska[half * 2048 + CAPS], CAPS,
           &skb[half * 2048], tt * 8);
  }
  __syncthreads();
  // Round 2: skb[0:2048] ∪ skb[2048:4096] -> ska[0:4096] (512 thr × 8)
  merge8(&skb[0], 2048, &skb[2048], 2048, &ska[0], t * 8);
  __syncthreads();

  // wave-0 sequential accept over sorted prefix, 64 candidates per group.
  // Equivalence to reference greedy NMS: suppressed boxes never suppress
  // others and IoU is symmetric, so scanning by descending score with
  // accept-iff-no-accepted-overlap reproduces the argmax loop exactly.
  if (threadIdx.x < 64) {
    int lane = threadIdx.x;
    int ac = 0;
    for (int gbase = 0; gbase < CAP && ac < MAX_DET; gbase += 64) {
      if (gbase >= K) break;
      __asm__ __volatile__("" ::: "memory");
      unsigned long long key = ska[gbase + lane];
      bool alive = (key != 0ull);
      float4 b = make_float4(0.f, 0.f, 0.f, 0.f);
      float area = 0.f;
      if (alive) {
        unsigned int pay = ~(unsigned int)key;  // (idx<<7)|cls
        int idx = (int)(pay >> 7);
        b = boxes[idx];
        area = (b.z - b.x) * (b.w - b.y);
      }
      for (int a2 = 0; a2 < ac; ++a2) {         // prefilter vs accepted
        if (alive) {
          float4 ab = abox[a2];
          float lx = fmaxf(ab.x, b.x), ly = fmaxf(ab.y, b.y);
          float rx = fminf(ab.z, b.z), ry = fminf(ab.w, b.w);
          float iw = fmaxf(rx - lx, 0.f), ih = fmaxf(ry - ly, 0.f);
          float inter = iw * ih;
          float iou = inter / (aarea[a2] + area - inter + 1e-9f);
          if (iou > 0.5f) alive = false;
        }
      }
      while (ac < MAX_DET) {                    // in-group ordered resolution
        unsigned long long mv = __ballot(alive);
        if (mv == 0ull) break;
        int first = __ffsll(mv) - 1;
        float wx1 = __shfl(b.x, first), wy1 = __shfl(b.y, first);
        float wx2 = __shfl(b.z, first), wy2 = __shfl(b.w, first);
        float wa  = __shfl(area, first);
        if (lane == first) {
          abox[ac] = b; aarea[ac] = area; akey[ac] = key;
          alive = false;
        }
        __asm__ __volatile__("" ::: "memory");
        if (alive) {
          float lx = fmaxf(wx1, b.x), ly = fmaxf(wy1, b.y);
          float rx = fminf(wx2, b.z), ry = fminf(wy2, b.w);
          float iw = fmaxf(rx - lx, 0.f), ih = fmaxf(ry - ly, 0.f);
          float inter = iw * ih;
          float iou = inter / (wa + area - inter + 1e-9f);
          if (iou > 0.5f) alive = false;
        }
        ++ac;
      }
    }
    if (lane == 0) acount = ac;
  }
  __syncthreads();

  // outputs: boxes[100*4] | ids[100] | scores[100] (ids as float, -1 invalid)
  if (t < MAX_DET) {
    float bx1 = 0.f, by1 = 0.f, bx2 = 0.f, by2 = 0.f, idf = -1.f, sc = 0.f;
    if (t < acount) {
      unsigned long long key = akey[t];
      float4 b = abox[t];
      bx1 = b.x; by1 = b.y; bx2 = b.z; by2 = b.w;
      unsigned int pay = ~(unsigned int)key;
      int clsid = (int)(pay & 0x7Fu);
      idf = (float)(clsid - 1);
      sc = __uint_as_float((unsigned int)(key >> 32));
    }
    out[t * 4 + 0] = bx1; out[t * 4 + 1] = by1;
    out[t * 4 + 2] = bx2; out[t * 4 + 3] = by2;
    out[400 + t] = idf;
    out[500 + t] = sc;
  }
}

// ---------------------------------------------------------------- launch
extern "C" void kernel_launch(void* const* d_in, const int* in_sizes, int n_in,
                              void* d_out, int out_size, void* d_ws, size_t ws_size,
                              hipStream_t stream) {
  (void)in_sizes; (void)n_in; (void)out_size; (void)ws_size;
  const float* pred = (const float*)d_in[0];
  const float* dbx  = (const float*)d_in[1];
  float* out = (float*)d_out;

  char* ws = (char*)d_ws;
  float4*             boxes = (float4*)(ws);                        // 3,200,000 B
  unsigned long long* keys  = (unsigned long long*)(ws + 3200000);  // 1,600,000 B
  unsigned int*       hist  = (unsigned int*)(ws + 4800000);        // 2,097,152 B
  unsigned int*       csums = (unsigned int*)(ws + 6897152);        //     4,096 B
  int*                ctr   = (int*)(ws + 6901248);                 //        16 B
  unsigned int*       thr   = (unsigned int*)(ws + 6901264);        //        16 B
  unsigned long long* cand  = (unsigned long long*)(ws + 6901280);  //    32,768 B

  hipLaunchKernelGGL(zero_kernel, dim3((NREP * NBUCKETS) / 256), dim3(256), 0, stream,
                     hist, ctr);
  hipLaunchKernelGGL(decode_kernel, dim3((N_TILES + 1) / 2), dim3(128), 0, stream,
                     pred, dbx, boxes, keys, hist);
  hipLaunchKernelGGL(chunksum_kernel, dim3(NBUCKETS / 256), dim3(256), 0, stream,
                     hist, csums);
  hipLaunchKernelGGL(thresh_kernel, dim3(1), dim3(1024), 0, stream,
                     hist, csums, thr);
  hipLaunchKernelGGL(compact_kernel, dim3((N_ANCHORS + 255) / 256), dim3(256), 0, stream,
                     keys, thr, cand, ctr);
  hipLaunchKernelGGL(sort4_kernel, dim3(4), dim3(256), 0, stream,
                     cand, ctr);
  hipLaunchKernelGGL(nms_kernel, dim3(1), dim3(512), 0, stream,
                     cand, ctr, boxes, out);
}